// Round 4
// baseline (931.870 us; speedup 1.0000x reference)
//
#include <hip/hip_runtime.h>

#define Bn 2
#define Cn 64
#define Hn 224
#define Wn 224
#define HWn (Hn*Wn)
#define WSn 32
#define OVn 8
#define STRIDEn 24
#define NHn 9
#define NWn 9
#define NWT 28                 // W/8 tiles per row
#define VROW (NWT*Cn*8)        // 14336 elements per (b,h) row in vb2
#define QSCALE (1.44269504088896f/32.0f)

typedef __bf16 bf16x8 __attribute__((ext_vector_type(8)));
typedef float f32x16 __attribute__((ext_vector_type(16)));
typedef unsigned int uint4v __attribute__((ext_vector_type(4)));

union PackU { uint4v u; bf16x8 h; };
union BfPair { __bf16 h[2]; unsigned u; };

__device__ __forceinline__ float fast_exp2(float x) {
#if __has_builtin(__builtin_amdgcn_exp2f)
  return __builtin_amdgcn_exp2f(x);
#else
  return exp2f(x);
#endif
}

// fade weight factor for window index i, in-window position p
__device__ __forceinline__ float edge_w(int i, int p) {
  float w = 1.0f;
  if (i > 0 && p < OVn)            w *= (float)p * (1.0f/7.0f);
  if (i < NHn-1 && p >= WSn-OVn)   w *= (float)(WSn-1-p) * (1.0f/7.0f);
  return w;
}

// separable coverage sum
__device__ __forceinline__ float covsum(int h) {
  int ihi = h / STRIDEn; if (ihi > NHn-1) ihi = NHn-1;
  float s = edge_w(ihi, h - STRIDEn*ihi);
  int ilo = ihi - 1;
  if (ilo >= 0) {
    int p = h - STRIDEn*ilo;
    if (p < WSn) s += edge_w(ilo, p);
  }
  return s;
}

// ---------------- QKV projection: fp32 in, bf16 out ----------------
// qb: [pix][8] bf16, PRE-SCALED by log2e/32.  kb: [pix][8] bf16.
// vb2: [b][h][w/8][c][w%8] bf16 (w8-tiled, for coalesced PV fragment loads).
__global__ __launch_bounds__(256) void qkv_kernel(
    const float* __restrict__ x,
    const float* __restrict__ Wq, const float* __restrict__ bq,
    const float* __restrict__ Wk, const float* __restrict__ bk,
    const float* __restrict__ Wv, const float* __restrict__ bv,
    __bf16* __restrict__ qb, __bf16* __restrict__ kb, __bf16* __restrict__ vb2)
{
  __shared__ float sW[80*64];   // rows 0-7: Wq, 8-15: Wk, 16-79: Wv
  __shared__ float sb[80];
  int tid = threadIdx.x;
  for (int i = tid; i < 8*64; i += 256) { sW[i] = Wq[i]; sW[512 + i] = Wk[i]; }
  for (int i = tid; i < 64*64; i += 256) sW[1024 + i] = Wv[i];
  if (tid < 8)  { sb[tid] = bq[tid]; sb[8 + tid] = bk[tid]; }
  if (tid >= 64 && tid < 128) sb[16 + (tid - 64)] = bv[tid - 64];
  __syncthreads();

  int pix = blockIdx.x * 256 + tid;      // B*H*W = 100352 = 392*256
  int b  = pix / HWn;
  int hw = pix - b * HWn;
  const float* xp = x + (size_t)b * Cn * HWn + hw;
  float xr[64];
  #pragma unroll
  for (int c = 0; c < 64; ++c) xr[c] = xp[(size_t)c * HWn];

  float q8[8], k8[8];
  #pragma unroll
  for (int o = 0; o < 8; ++o) {
    const float4* wrq = (const float4*)(sW + o*64);
    const float4* wrk = (const float4*)(sW + 512 + o*64);
    float sq = sb[o], sk = sb[8+o];
    #pragma unroll
    for (int c4 = 0; c4 < 16; ++c4) {
      float4 wq4 = wrq[c4]; float4 wk4 = wrk[c4];
      sq = fmaf(wq4.x, xr[4*c4+0], sq); sq = fmaf(wq4.y, xr[4*c4+1], sq);
      sq = fmaf(wq4.z, xr[4*c4+2], sq); sq = fmaf(wq4.w, xr[4*c4+3], sq);
      sk = fmaf(wk4.x, xr[4*c4+0], sk); sk = fmaf(wk4.y, xr[4*c4+1], sk);
      sk = fmaf(wk4.z, xr[4*c4+2], sk); sk = fmaf(wk4.w, xr[4*c4+3], sk);
    }
    q8[o] = sq; k8[o] = sk;
  }
  PackU qo, ko;
  #pragma unroll
  for (int o = 0; o < 8; ++o) {
    qo.h[o] = (__bf16)(q8[o] * QSCALE);
    ko.h[o] = (__bf16)k8[o];
  }
  *(uint4v*)(qb + (size_t)pix*8) = qo.u;
  *(uint4v*)(kb + (size_t)pix*8) = ko.u;

  int h = hw / Wn, w = hw - h*Wn;
  __bf16* vo = vb2 + ((((size_t)b*Hn + h)*NWT + (w >> 3))*Cn)*8 + (w & 7);
  for (int og = 0; og < 16; ++og) {
    #pragma unroll
    for (int t = 0; t < 4; ++t) {
      int o = og*4 + t;
      const float4* wr = (const float4*)(sW + 1024 + o*64);
      float s = sb[16+o];
      #pragma unroll
      for (int c4 = 0; c4 < 16; ++c4) {
        float4 w4 = wr[c4];
        s = fmaf(w4.x, xr[4*c4+0], s); s = fmaf(w4.y, xr[4*c4+1], s);
        s = fmaf(w4.z, xr[4*c4+2], s); s = fmaf(w4.w, xr[4*c4+3], s);
      }
      vo[(size_t)o * 8] = (__bf16)s;
    }
  }
}

// ---------------- MFMA flash attention ----------------
// Block = 512 threads = 8 waves = one window x 4 query-rows x 2 key-halves.
// Grid = 162 windows * 8 row-groups = 1296 blocks.
__global__ __launch_bounds__(512, 8) void attn_kernel(
    const __bf16* __restrict__ qb, const __bf16* __restrict__ kb,
    const __bf16* __restrict__ vb2, float* __restrict__ outacc)
{
  __shared__ float LB[4*64*33];   // merge buffers; reused as per-wave transpose tiles

  // XCD swizzle: 1296 = 8*162; consecutive bidm (same window) on same XCD.
  int bid = blockIdx.x;
  int bidm = (bid & 7) * 162 + (bid >> 3);
  int win = bidm >> 3;            // 0..161
  int rg  = bidm & 7;             // row-group 0..7
  int b  = win / (NHn*NWn);
  int ij = win - b*(NHn*NWn);
  int wi = ij / NWn;
  int wj = ij - wi*NWn;

  int tid  = threadIdx.x;
  int widx = tid >> 6;            // wave 0..7
  int lane = tid & 63;
  int qrow = widx >> 1;           // 0..3
  int khalf = widx & 1;           // 0..1 (key rows 0..15 / 16..31)
  int ph = rg*4 + qrow;
  int lo = lane & 31, hi = lane >> 5;
  int h0 = wi*STRIDEn, w0 = wj*STRIDEn;

  // Q fragment (B operand): lane holds Q[query=lo][ch=8*hi+j]; hi lanes zeroed (ch 8..15 pad)
  bf16x8 qf = *(const bf16x8*)(qb + ((size_t)(b*Hn + h0 + ph)*Wn + w0 + lo) * 8);
  if (hi) qf = (bf16x8){};

  // K rows for this key-half; hi lanes duplicate (annihilated by qf==0 rows)
  const __bf16* kbase = kb + ((size_t)(b*Hn + h0 + khalf*16)*Wn + w0 + lo) * 8;
  // V in w8-tiled layout; vbase points at (ch=lo, wtile=w0/8 + hi)
  const __bf16* vbase = vb2 + ((((size_t)(b*Hn + h0 + khalf*16))*NWT + (w0>>3))*Cn + lo)*8
                        + (size_t)hi*512;

  f32x16 acc0 = {}, acc1 = {};
  float lsum = 0.f;

  #pragma unroll 2
  for (int kt = 0; kt < 16; ++kt) {
    bf16x8 kf = *(const bf16x8*)(kbase + (size_t)kt*Wn*8);

    const __bf16* vk = vbase + (size_t)kt*VROW;
    bf16x8 vf00 = *(const bf16x8*)(vk);           // keys 8*hi+j,    ch lo
    bf16x8 vf01 = *(const bf16x8*)(vk + 256);     // keys 8*hi+j,    ch lo+32
    bf16x8 vf10 = *(const bf16x8*)(vk + 1024);    // keys 16+8*hi+j, ch lo
    bf16x8 vf11 = *(const bf16x8*)(vk + 1280);    // keys 16+8*hi+j, ch lo+32

    // S[key][query]: key=(r&3)+8*(r>>2)+4*hi, query=lo. Scores in log2 domain.
    f32x16 s = __builtin_amdgcn_mfma_f32_32x32x16_bf16(kf, qf, (f32x16){}, 0, 0, 0);

    unsigned w[8];
    #pragma unroll
    for (int d = 0; d < 8; ++d) {
      float a  = fast_exp2(s[2*d]);
      float b2 = fast_exp2(s[2*d+1]);
      lsum += a + b2;
      BfPair pr; pr.h[0] = (__bf16)a; pr.h[1] = (__bf16)b2;
      w[d] = pr.u;
    }
    unsigned pw[8];
    #pragma unroll
    for (int d = 0; d < 8; ++d) pw[d] = __shfl_xor(w[d], 32);

    PackU pa0, pa1;
    pa0.u = (uint4v){ hi ? pw[2] : w[0],  hi ? pw[3] : w[1],
                      hi ? w[2]  : pw[0], hi ? w[3]  : pw[1] };
    pa1.u = (uint4v){ hi ? pw[6] : w[4],  hi ? pw[7] : w[5],
                      hi ? w[6]  : pw[4], hi ? w[7]  : pw[5] };

    acc0 = __builtin_amdgcn_mfma_f32_32x32x16_bf16(pa0.h, vf00, acc0, 0, 0, 0);
    acc1 = __builtin_amdgcn_mfma_f32_32x32x16_bf16(pa0.h, vf01, acc1, 0, 0, 0);
    acc0 = __builtin_amdgcn_mfma_f32_32x32x16_bf16(pa1.h, vf10, acc0, 0, 0, 0);
    acc1 = __builtin_amdgcn_mfma_f32_32x32x16_bf16(pa1.h, vf11, acc1, 0, 0, 0);
  }

  // within-wave: partner half-wave holds the other 16 keys of every tile
  lsum += __shfl_xor(lsum, 32);

  // merge the two key-halves (plain sums -> addition suffices)
  float* mb = LB + (size_t)qrow*64*33 + (size_t)lane*33;
  if (khalf) {
    #pragma unroll
    for (int r = 0; r < 16; ++r) { mb[r] = acc0[r]; mb[16+r] = acc1[r]; }
    mb[32] = lsum;
  }
  __syncthreads();
  if (!khalf) {
    #pragma unroll
    for (int r = 0; r < 16; ++r) { acc0[r] += mb[r]; acc1[r] += mb[16+r]; }
    lsum += mb[32];
  }
  __syncthreads();
  if (khalf) return;

  float sc = edge_w(wi, ph) * edge_w(wj, lo) / lsum;   // lane's query = lo
  int qh = h0 + ph;
  float* ob = outacc + (size_t)b*Cn*HWn + (size_t)qh*Wn + w0;
  float* T = LB + (size_t)qrow*1056;   // [32][33] per qrow wave

  // acc layout: D[query=(r&3)+8*(r>>2)+4*hi][ch=lo]; transpose so atomics
  // are coalesced along w (query) with ch strided.
  #pragma unroll
  for (int r = 0; r < 16; ++r) T[((r&3) + 8*(r>>2) + 4*hi)*33 + lo] = acc0[r];
  #pragma unroll
  for (int rr = 0; rr < 16; ++rr)
    atomicAdd(ob + (size_t)(2*rr + hi)*HWn + lo, T[lo*33 + 2*rr + hi] * sc);
  #pragma unroll
  for (int r = 0; r < 16; ++r) T[((r&3) + 8*(r>>2) + 4*hi)*33 + lo] = acc1[r];
  #pragma unroll
  for (int rr = 0; rr < 16; ++rr)
    atomicAdd(ob + (size_t)(32 + 2*rr + hi)*HWn + lo, T[lo*33 + 2*rr + hi] * sc);
}

// ---------------- final blend: out = x + gamma * acc/(cnt+1e-8) ----------------
__global__ __launch_bounds__(256) void final_kernel(
    const float* __restrict__ x, const float* __restrict__ gamma,
    float* __restrict__ out)
{
  int idx4 = blockIdx.x * 256 + threadIdx.x;
  int w4    = idx4 % (Wn/4);
  int rowid = idx4 / (Wn/4);
  int h = rowid % Hn;
  float g = gamma[0];
  float rs = covsum(h);
  int w0 = w4*4;
  float c0 = rs * covsum(w0+0) + 1e-8f;
  float c1 = rs * covsum(w0+1) + 1e-8f;
  float c2 = rs * covsum(w0+2) + 1e-8f;
  float c3 = rs * covsum(w0+3) + 1e-8f;
  float4 xv = ((const float4*)x)[idx4];
  float4 av = ((float4*)out)[idx4];
  float4 r;
  r.x = xv.x + g * av.x / c0;
  r.y = xv.y + g * av.y / c1;
  r.z = xv.z + g * av.z / c2;
  r.w = xv.w + g * av.w / c3;
  ((float4*)out)[idx4] = r;
}

extern "C" void kernel_launch(void* const* d_in, const int* in_sizes, int n_in,
                              void* d_out, int out_size, void* d_ws, size_t ws_size,
                              hipStream_t stream) {
  const float* x     = (const float*)d_in[0];
  const float* Wq    = (const float*)d_in[1];
  const float* bq    = (const float*)d_in[2];
  const float* Wk    = (const float*)d_in[3];
  const float* bk    = (const float*)d_in[4];
  const float* Wv    = (const float*)d_in[5];
  const float* bv    = (const float*)d_in[6];
  const float* gamma = (const float*)d_in[7];
  float* out = (float*)d_out;

  __bf16* qb  = (__bf16*)d_ws;                       // B*H*W*8
  __bf16* kb  = qb + (size_t)Bn*HWn*8;               // B*H*W*8
  __bf16* vb2 = kb + (size_t)Bn*HWn*8;               // B*C*H*W (w8-tiled)

  hipMemsetAsync(d_out, 0, (size_t)out_size * sizeof(float), stream);
  qkv_kernel<<<(Bn*HWn)/256, 256, 0, stream>>>(x, Wq, bq, Wk, bk, Wv, bv, qb, kb, vb2);
  attn_kernel<<<Bn*NHn*NWn*8, 512, 0, stream>>>(qb, kb, vb2, out);
  final_kernel<<<(Bn*Cn*HWn/4)/256, 256, 0, stream>>>(x, gamma, out);
}

// Round 5
// 131.391 us; speedup vs baseline: 7.0923x; 7.0923x over previous
//
#include <hip/hip_runtime.h>

#define Bn 2
#define Cn 64
#define Hn 224
#define Wn 224
#define HWn (Hn*Wn)
#define WSn 32
#define OVn 8
#define STRIDEn 24
#define NHn 9
#define NWn 9
#define NWT 28                 // W/8 tiles per row
#define VROW (NWT*Cn*8)        // 14336 elements per (b,h) row in vb2
#define QSCALE (1.44269504088896f/32.0f)

typedef __bf16 bf16x8 __attribute__((ext_vector_type(8)));
typedef float f32x16 __attribute__((ext_vector_type(16)));
typedef unsigned int uint4v __attribute__((ext_vector_type(4)));

union PackU { uint4v u; bf16x8 h; };
union BfPair { __bf16 h[2]; unsigned u; };

__device__ __forceinline__ float fast_exp2(float x) {
#if __has_builtin(__builtin_amdgcn_exp2f)
  return __builtin_amdgcn_exp2f(x);
#else
  return exp2f(x);
#endif
}

// fade weight factor for window index i, in-window position p
__device__ __forceinline__ float edge_w(int i, int p) {
  float w = 1.0f;
  if (i > 0 && p < OVn)            w *= (float)p * (1.0f/7.0f);
  if (i < NHn-1 && p >= WSn-OVn)   w *= (float)(WSn-1-p) * (1.0f/7.0f);
  return w;
}

// separable coverage sum
__device__ __forceinline__ float covsum(int h) {
  int ihi = h / STRIDEn; if (ihi > NHn-1) ihi = NHn-1;
  float s = edge_w(ihi, h - STRIDEn*ihi);
  int ilo = ihi - 1;
  if (ilo >= 0) {
    int p = h - STRIDEn*ilo;
    if (p < WSn) s += edge_w(ilo, p);
  }
  return s;
}

// ---------------- QKV projection: fp32 in, bf16 out ----------------
// qb: [pix][8] bf16, PRE-SCALED by log2e/32.  kb: [pix][8] bf16.
// vb2: [b][h][w/8][c][w%8] bf16 (w8-tiled, for coalesced PV fragment loads).
__global__ __launch_bounds__(256) void qkv_kernel(
    const float* __restrict__ x,
    const float* __restrict__ Wq, const float* __restrict__ bq,
    const float* __restrict__ Wk, const float* __restrict__ bk,
    const float* __restrict__ Wv, const float* __restrict__ bv,
    __bf16* __restrict__ qb, __bf16* __restrict__ kb, __bf16* __restrict__ vb2)
{
  __shared__ float sW[80*64];   // rows 0-7: Wq, 8-15: Wk, 16-79: Wv
  __shared__ float sb[80];
  int tid = threadIdx.x;
  for (int i = tid; i < 8*64; i += 256) { sW[i] = Wq[i]; sW[512 + i] = Wk[i]; }
  for (int i = tid; i < 64*64; i += 256) sW[1024 + i] = Wv[i];
  if (tid < 8)  { sb[tid] = bq[tid]; sb[8 + tid] = bk[tid]; }
  if (tid >= 64 && tid < 128) sb[16 + (tid - 64)] = bv[tid - 64];
  __syncthreads();

  int pix = blockIdx.x * 256 + tid;      // B*H*W = 100352 = 392*256
  int b  = pix / HWn;
  int hw = pix - b * HWn;
  const float* xp = x + (size_t)b * Cn * HWn + hw;
  float xr[64];
  #pragma unroll
  for (int c = 0; c < 64; ++c) xr[c] = xp[(size_t)c * HWn];

  float q8[8], k8[8];
  #pragma unroll
  for (int o = 0; o < 8; ++o) {
    const float4* wrq = (const float4*)(sW + o*64);
    const float4* wrk = (const float4*)(sW + 512 + o*64);
    float sq = sb[o], sk = sb[8+o];
    #pragma unroll
    for (int c4 = 0; c4 < 16; ++c4) {
      float4 wq4 = wrq[c4]; float4 wk4 = wrk[c4];
      sq = fmaf(wq4.x, xr[4*c4+0], sq); sq = fmaf(wq4.y, xr[4*c4+1], sq);
      sq = fmaf(wq4.z, xr[4*c4+2], sq); sq = fmaf(wq4.w, xr[4*c4+3], sq);
      sk = fmaf(wk4.x, xr[4*c4+0], sk); sk = fmaf(wk4.y, xr[4*c4+1], sk);
      sk = fmaf(wk4.z, xr[4*c4+2], sk); sk = fmaf(wk4.w, xr[4*c4+3], sk);
    }
    q8[o] = sq; k8[o] = sk;
  }
  PackU qo, ko;
  #pragma unroll
  for (int o = 0; o < 8; ++o) {
    qo.h[o] = (__bf16)(q8[o] * QSCALE);
    ko.h[o] = (__bf16)k8[o];
  }
  *(uint4v*)(qb + (size_t)pix*8) = qo.u;
  *(uint4v*)(kb + (size_t)pix*8) = ko.u;

  int h = hw / Wn, w = hw - h*Wn;
  __bf16* vo = vb2 + ((((size_t)b*Hn + h)*NWT + (w >> 3))*Cn)*8 + (w & 7);
  for (int og = 0; og < 16; ++og) {
    #pragma unroll
    for (int t = 0; t < 4; ++t) {
      int o = og*4 + t;
      const float4* wr = (const float4*)(sW + 1024 + o*64);
      float s = sb[16+o];
      #pragma unroll
      for (int c4 = 0; c4 < 16; ++c4) {
        float4 w4 = wr[c4];
        s = fmaf(w4.x, xr[4*c4+0], s); s = fmaf(w4.y, xr[4*c4+1], s);
        s = fmaf(w4.z, xr[4*c4+2], s); s = fmaf(w4.w, xr[4*c4+3], s);
      }
      vo[(size_t)o * 8] = (__bf16)s;
    }
  }
}

// ---------------- MFMA flash attention ----------------
// Block = 512 threads = 8 waves = one window x 4 query-rows x 2 key-halves.
// Grid = 162 windows * 8 row-groups = 1296 blocks.
// launch_bounds min-waves MUST stay <=4: (512,8) caps VGPR at 64 -> acc spills
// to scratch -> 2.8 GB HBM traffic, 8x regression (measured round 4).
__global__ __launch_bounds__(512, 4) void attn_kernel(
    const __bf16* __restrict__ qb, const __bf16* __restrict__ kb,
    const __bf16* __restrict__ vb2, float* __restrict__ outacc)
{
  __shared__ float LB[4*64*33];   // merge buffers; reused as per-wave transpose tiles

  // XCD swizzle: 1296 = 8*162; consecutive bidm (same window) on same XCD.
  int bid = blockIdx.x;
  int bidm = (bid & 7) * 162 + (bid >> 3);
  int win = bidm >> 3;            // 0..161
  int rg  = bidm & 7;             // row-group 0..7
  int b  = win / (NHn*NWn);
  int ij = win - b*(NHn*NWn);
  int wi = ij / NWn;
  int wj = ij - wi*NWn;

  int tid  = threadIdx.x;
  int widx = tid >> 6;            // wave 0..7
  int lane = tid & 63;
  int qrow = widx >> 1;           // 0..3
  int khalf = widx & 1;           // 0..1 (key rows 0..15 / 16..31)
  int ph = rg*4 + qrow;
  int lo = lane & 31, hi = lane >> 5;
  int h0 = wi*STRIDEn, w0 = wj*STRIDEn;

  // Q fragment (B operand): lane holds Q[query=lo][ch=8*hi+j]; hi lanes zeroed (ch 8..15 pad)
  bf16x8 qf = *(const bf16x8*)(qb + ((size_t)(b*Hn + h0 + ph)*Wn + w0 + lo) * 8);
  if (hi) qf = (bf16x8){};

  // K rows for this key-half; hi lanes duplicate (annihilated by qf==0 rows)
  const __bf16* kbase = kb + ((size_t)(b*Hn + h0 + khalf*16)*Wn + w0 + lo) * 8;
  // V in w8-tiled layout; vbase points at (ch=lo, wtile=w0/8 + hi)
  const __bf16* vbase = vb2 + ((((size_t)(b*Hn + h0 + khalf*16))*NWT + (w0>>3))*Cn + lo)*8
                        + (size_t)hi*512;

  f32x16 acc0 = {}, acc1 = {};
  float lsum = 0.f;

  #pragma unroll 2
  for (int kt = 0; kt < 16; ++kt) {
    bf16x8 kf = *(const bf16x8*)(kbase + (size_t)kt*Wn*8);

    const __bf16* vk = vbase + (size_t)kt*VROW;
    bf16x8 vf00 = *(const bf16x8*)(vk);           // keys 8*hi+j,    ch lo
    bf16x8 vf01 = *(const bf16x8*)(vk + 256);     // keys 8*hi+j,    ch lo+32
    bf16x8 vf10 = *(const bf16x8*)(vk + 1024);    // keys 16+8*hi+j, ch lo
    bf16x8 vf11 = *(const bf16x8*)(vk + 1280);    // keys 16+8*hi+j, ch lo+32

    // S[key][query]: key=(r&3)+8*(r>>2)+4*hi, query=lo. Scores in log2 domain.
    f32x16 s = __builtin_amdgcn_mfma_f32_32x32x16_bf16(kf, qf, (f32x16){}, 0, 0, 0);

    unsigned w[8];
    #pragma unroll
    for (int d = 0; d < 8; ++d) {
      float a  = fast_exp2(s[2*d]);
      float b2 = fast_exp2(s[2*d+1]);
      lsum += a + b2;
      BfPair pr; pr.h[0] = (__bf16)a; pr.h[1] = (__bf16)b2;
      w[d] = pr.u;
    }
    unsigned pw[8];
    #pragma unroll
    for (int d = 0; d < 8; ++d) pw[d] = __shfl_xor(w[d], 32);

    PackU pa0, pa1;
    pa0.u = (uint4v){ hi ? pw[2] : w[0],  hi ? pw[3] : w[1],
                      hi ? w[2]  : pw[0], hi ? w[3]  : pw[1] };
    pa1.u = (uint4v){ hi ? pw[6] : w[4],  hi ? pw[7] : w[5],
                      hi ? w[6]  : pw[4], hi ? w[7]  : pw[5] };

    acc0 = __builtin_amdgcn_mfma_f32_32x32x16_bf16(pa0.h, vf00, acc0, 0, 0, 0);
    acc1 = __builtin_amdgcn_mfma_f32_32x32x16_bf16(pa0.h, vf01, acc1, 0, 0, 0);
    acc0 = __builtin_amdgcn_mfma_f32_32x32x16_bf16(pa1.h, vf10, acc0, 0, 0, 0);
    acc1 = __builtin_amdgcn_mfma_f32_32x32x16_bf16(pa1.h, vf11, acc1, 0, 0, 0);
  }

  // within-wave: partner half-wave holds the other 16 keys of every tile
  lsum += __shfl_xor(lsum, 32);

  // merge the two key-halves (plain sums -> addition suffices)
  float* mb = LB + (size_t)qrow*64*33 + (size_t)lane*33;
  if (khalf) {
    #pragma unroll
    for (int r = 0; r < 16; ++r) { mb[r] = acc0[r]; mb[16+r] = acc1[r]; }
    mb[32] = lsum;
  }
  __syncthreads();
  if (!khalf) {
    #pragma unroll
    for (int r = 0; r < 16; ++r) { acc0[r] += mb[r]; acc1[r] += mb[16+r]; }
    lsum += mb[32];
  }
  __syncthreads();
  if (khalf) return;

  float sc = edge_w(wi, ph) * edge_w(wj, lo) / lsum;   // lane's query = lo
  int qh = h0 + ph;
  float* ob = outacc + (size_t)b*Cn*HWn + (size_t)qh*Wn + w0;
  float* T = LB + (size_t)qrow*1056;   // [32][33] per qrow wave

  // acc layout: D[query=(r&3)+8*(r>>2)+4*hi][ch=lo]; transpose so atomics
  // are coalesced along w (query) with ch strided.
  #pragma unroll
  for (int r = 0; r < 16; ++r) T[((r&3) + 8*(r>>2) + 4*hi)*33 + lo] = acc0[r];
  #pragma unroll
  for (int rr = 0; rr < 16; ++rr)
    atomicAdd(ob + (size_t)(2*rr + hi)*HWn + lo, T[lo*33 + 2*rr + hi] * sc);
  #pragma unroll
  for (int r = 0; r < 16; ++r) T[((r&3) + 8*(r>>2) + 4*hi)*33 + lo] = acc1[r];
  #pragma unroll
  for (int rr = 0; rr < 16; ++rr)
    atomicAdd(ob + (size_t)(32 + 2*rr + hi)*HWn + lo, T[lo*33 + 2*rr + hi] * sc);
}

// ---------------- final blend: out = x + gamma * acc/(cnt+1e-8) ----------------
__global__ __launch_bounds__(256) void final_kernel(
    const float* __restrict__ x, const float* __restrict__ gamma,
    float* __restrict__ out)
{
  int idx4 = blockIdx.x * 256 + threadIdx.x;
  int w4    = idx4 % (Wn/4);
  int rowid = idx4 / (Wn/4);
  int h = rowid % Hn;
  float g = gamma[0];
  float rs = covsum(h);
  int w0 = w4*4;
  float c0 = rs * covsum(w0+0) + 1e-8f;
  float c1 = rs * covsum(w0+1) + 1e-8f;
  float c2 = rs * covsum(w0+2) + 1e-8f;
  float c3 = rs * covsum(w0+3) + 1e-8f;
  float4 xv = ((const float4*)x)[idx4];
  float4 av = ((float4*)out)[idx4];
  float4 r;
  r.x = xv.x + g * av.x / c0;
  r.y = xv.y + g * av.y / c1;
  r.z = xv.z + g * av.z / c2;
  r.w = xv.w + g * av.w / c3;
  ((float4*)out)[idx4] = r;
}

extern "C" void kernel_launch(void* const* d_in, const int* in_sizes, int n_in,
                              void* d_out, int out_size, void* d_ws, size_t ws_size,
                              hipStream_t stream) {
  const float* x     = (const float*)d_in[0];
  const float* Wq    = (const float*)d_in[1];
  const float* bq    = (const float*)d_in[2];
  const float* Wk    = (const float*)d_in[3];
  const float* bk    = (const float*)d_in[4];
  const float* Wv    = (const float*)d_in[5];
  const float* bv    = (const float*)d_in[6];
  const float* gamma = (const float*)d_in[7];
  float* out = (float*)d_out;

  __bf16* qb  = (__bf16*)d_ws;                       // B*H*W*8
  __bf16* kb  = qb + (size_t)Bn*HWn*8;               // B*H*W*8
  __bf16* vb2 = kb + (size_t)Bn*HWn*8;               // B*C*H*W (w8-tiled)

  hipMemsetAsync(d_out, 0, (size_t)out_size * sizeof(float), stream);
  qkv_kernel<<<(Bn*HWn)/256, 256, 0, stream>>>(x, Wq, bq, Wk, bk, Wv, bv, qb, kb, vb2);
  attn_kernel<<<Bn*NHn*NWn*8, 512, 0, stream>>>(qb, kb, vb2, out);
  final_kernel<<<(Bn*Cn*HWn/4)/256, 256, 0, stream>>>(x, gamma, out);
}

// Round 6
// 125.464 us; speedup vs baseline: 7.4274x; 1.0472x over previous
//
#include <hip/hip_runtime.h>

#define Bn 2
#define Cn 64
#define Hn 224
#define Wn 224
#define HWn (Hn*Wn)
#define WSn 32
#define OVn 8
#define STRIDEn 24
#define NHn 9
#define NWn 9
#define NWT 28                 // W/8 tiles per row
#define VROW (NWT*Cn*8)        // 14336 elements per (b,h) row in vb2
#define QSCALE (1.44269504088896f/32.0f)

typedef __bf16 bf16x8 __attribute__((ext_vector_type(8)));
typedef float f32x16 __attribute__((ext_vector_type(16)));
typedef unsigned int uint4v __attribute__((ext_vector_type(4)));

union PackU { uint4v u; bf16x8 h; };
union BfPair { __bf16 h[2]; unsigned u; };

__device__ __forceinline__ float fast_exp2(float x) {
#if __has_builtin(__builtin_amdgcn_exp2f)
  return __builtin_amdgcn_exp2f(x);
#else
  return exp2f(x);
#endif
}

// fade weight factor for window index i, in-window position p
__device__ __forceinline__ float edge_w(int i, int p) {
  float w = 1.0f;
  if (i > 0 && p < OVn)            w *= (float)p * (1.0f/7.0f);
  if (i < NHn-1 && p >= WSn-OVn)   w *= (float)(WSn-1-p) * (1.0f/7.0f);
  return w;
}

// separable coverage sum
__device__ __forceinline__ float covsum(int h) {
  int ihi = h / STRIDEn; if (ihi > NHn-1) ihi = NHn-1;
  float s = edge_w(ihi, h - STRIDEn*ihi);
  int ilo = ihi - 1;
  if (ilo >= 0) {
    int p = h - STRIDEn*ilo;
    if (p < WSn) s += edge_w(ilo, p);
  }
  return s;
}

// ---------------- QKV projection: fp32 in, bf16 out ----------------
// 3-role split for wave parallelism (1568 -> 4704 waves):
//   role 0: q8 + k8;  role 1: v[0:32);  role 2: v[32:64).
// qb: [pix][8] bf16 PRE-SCALED by log2e/32.  kb: [pix][8] bf16.
// vb2: [b][h][w/8][c][w%8] bf16 (w8-tiled, coalesced PV fragment loads).
__global__ __launch_bounds__(256) void qkv_kernel(
    const float* __restrict__ x,
    const float* __restrict__ Wq, const float* __restrict__ bq,
    const float* __restrict__ Wk, const float* __restrict__ bk,
    const float* __restrict__ Wv, const float* __restrict__ bv,
    __bf16* __restrict__ qb, __bf16* __restrict__ kb, __bf16* __restrict__ vb2)
{
  __shared__ float sW[32*64];
  __shared__ float sb2[32];
  int bid = blockIdx.x;
  int pb = bid / 3, role = bid - pb*3;
  int tid = threadIdx.x;

  if (role == 0) {
    for (int i = tid; i < 8*64; i += 256) { sW[i] = Wq[i]; sW[512 + i] = Wk[i]; }
    if (tid < 8) { sb2[tid] = bq[tid]; sb2[8 + tid] = bk[tid]; }
  } else {
    const float* Wsrc = Wv + (size_t)(role-1)*32*64;
    for (int i = tid; i < 32*64; i += 256) sW[i] = Wsrc[i];
    if (tid < 32) sb2[tid] = bv[(role-1)*32 + tid];
  }
  __syncthreads();

  int pix = pb*256 + tid;                // B*H*W = 100352 = 392*256
  int b  = pix / HWn;
  int hw = pix - b * HWn;
  const float* xp = x + (size_t)b * Cn * HWn + hw;
  float xr[64];
  #pragma unroll
  for (int c = 0; c < 64; ++c) xr[c] = xp[(size_t)c * HWn];

  if (role == 0) {
    float q8[8], k8[8];
    #pragma unroll
    for (int o = 0; o < 8; ++o) {
      const float4* wrq = (const float4*)(sW + o*64);
      const float4* wrk = (const float4*)(sW + 512 + o*64);
      float sq = sb2[o], sk = sb2[8+o];
      #pragma unroll
      for (int c4 = 0; c4 < 16; ++c4) {
        float4 wq4 = wrq[c4]; float4 wk4 = wrk[c4];
        sq = fmaf(wq4.x, xr[4*c4+0], sq); sq = fmaf(wq4.y, xr[4*c4+1], sq);
        sq = fmaf(wq4.z, xr[4*c4+2], sq); sq = fmaf(wq4.w, xr[4*c4+3], sq);
        sk = fmaf(wk4.x, xr[4*c4+0], sk); sk = fmaf(wk4.y, xr[4*c4+1], sk);
        sk = fmaf(wk4.z, xr[4*c4+2], sk); sk = fmaf(wk4.w, xr[4*c4+3], sk);
      }
      q8[o] = sq; k8[o] = sk;
    }
    PackU qo, ko;
    #pragma unroll
    for (int o = 0; o < 8; ++o) {
      qo.h[o] = (__bf16)(q8[o] * QSCALE);
      ko.h[o] = (__bf16)k8[o];
    }
    *(uint4v*)(qb + (size_t)pix*8) = qo.u;
    *(uint4v*)(kb + (size_t)pix*8) = ko.u;
  } else {
    int h = hw / Wn, w = hw - h*Wn;
    __bf16* vo = vb2 + (((size_t)(b*Hn + h)*NWT + (w >> 3))*Cn + (size_t)(role-1)*32)*8 + (w & 7);
    for (int og = 0; og < 8; ++og) {
      #pragma unroll
      for (int t = 0; t < 4; ++t) {
        int o = og*4 + t;
        const float4* wr = (const float4*)(sW + o*64);
        float s = sb2[o];
        #pragma unroll
        for (int c4 = 0; c4 < 16; ++c4) {
          float4 w4 = wr[c4];
          s = fmaf(w4.x, xr[4*c4+0], s); s = fmaf(w4.y, xr[4*c4+1], s);
          s = fmaf(w4.z, xr[4*c4+2], s); s = fmaf(w4.w, xr[4*c4+3], s);
        }
        vo[(size_t)o * 8] = (__bf16)s;
      }
    }
  }
}

// ---------------- MFMA flash attention ----------------
// Block = 512 threads = 8 waves = one window x 4 query-rows x 2 key-halves.
// Grid = 162 windows * 8 row-groups = 1296 blocks.
// launch_bounds min-waves MUST stay <=4: (512,8) caps VGPR at 64 -> acc spills
// to scratch -> 2.8 GB HBM traffic, 8x regression (measured round 4).
__global__ __launch_bounds__(512, 4) void attn_kernel(
    const __bf16* __restrict__ qb, const __bf16* __restrict__ kb,
    const __bf16* __restrict__ vb2, float* __restrict__ outacc)
{
  __shared__ float LB[4*64*33];   // merge buffers; reused as per-wave transpose tiles

  // XCD swizzle: 1296 = 8*162; consecutive bidm (same window) on same XCD.
  int bid = blockIdx.x;
  int bidm = (bid & 7) * 162 + (bid >> 3);
  int win = bidm >> 3;            // 0..161
  int rg  = bidm & 7;             // row-group 0..7
  int b  = win / (NHn*NWn);
  int ij = win - b*(NHn*NWn);
  int wi = ij / NWn;
  int wj = ij - wi*NWn;

  int tid  = threadIdx.x;
  int widx = tid >> 6;            // wave 0..7
  int lane = tid & 63;
  int qrow = widx >> 1;           // 0..3
  int khalf = widx & 1;           // 0..1 (key rows 0..15 / 16..31)
  int ph = rg*4 + qrow;
  int lo = lane & 31, hi = lane >> 5;
  int h0 = wi*STRIDEn, w0 = wj*STRIDEn;

  // Q fragment (B operand): lane holds Q[query=lo][ch=8*hi+j]; hi lanes zeroed (ch 8..15 pad)
  bf16x8 qf = *(const bf16x8*)(qb + ((size_t)(b*Hn + h0 + ph)*Wn + w0 + lo) * 8);
  if (hi) qf = (bf16x8){};

  // K rows for this key-half; hi lanes duplicate (annihilated by qf==0 rows)
  const __bf16* kbase = kb + ((size_t)(b*Hn + h0 + khalf*16)*Wn + w0 + lo) * 8;
  // V in w8-tiled layout; vbase points at (ch=lo, wtile=w0/8 + hi)
  const __bf16* vbase = vb2 + ((((size_t)(b*Hn + h0 + khalf*16))*NWT + (w0>>3))*Cn + lo)*8
                        + (size_t)hi*512;

  f32x16 acc0 = {}, acc1 = {};
  float ls[4] = {0.f, 0.f, 0.f, 0.f};   // 4-way partial sums: break the serial add chain

  #pragma unroll 2
  for (int kt = 0; kt < 16; ++kt) {
    bf16x8 kf = *(const bf16x8*)(kbase + (size_t)kt*Wn*8);

    const __bf16* vk = vbase + (size_t)kt*VROW;
    bf16x8 vf00 = *(const bf16x8*)(vk);           // keys 8*hi+j,    ch lo
    bf16x8 vf01 = *(const bf16x8*)(vk + 256);     // keys 8*hi+j,    ch lo+32
    bf16x8 vf10 = *(const bf16x8*)(vk + 1024);    // keys 16+8*hi+j, ch lo
    bf16x8 vf11 = *(const bf16x8*)(vk + 1280);    // keys 16+8*hi+j, ch lo+32

    // S[key][query]: key=(r&3)+8*(r>>2)+4*hi, query=lo. Scores in log2 domain.
    f32x16 s = __builtin_amdgcn_mfma_f32_32x32x16_bf16(kf, qf, (f32x16){}, 0, 0, 0);

    unsigned w[8];
    #pragma unroll
    for (int d = 0; d < 8; ++d) {
      float a  = fast_exp2(s[2*d]);
      float b2 = fast_exp2(s[2*d+1]);
      ls[d & 3] += a + b2;
      BfPair pr; pr.h[0] = (__bf16)a; pr.h[1] = (__bf16)b2;
      w[d] = pr.u;
    }
    // permlane32_swap: new_dst = [dst.lo31 | src.lo31], new_src = [dst.hi31 | src.hi31]
    // -> one op yields BOTH PV-fragment words (replaces 2 shfl + 4 cndmask each).
    auto s02 = __builtin_amdgcn_permlane32_swap((int)w[0], (int)w[2], false, false);
    auto s13 = __builtin_amdgcn_permlane32_swap((int)w[1], (int)w[3], false, false);
    auto s46 = __builtin_amdgcn_permlane32_swap((int)w[4], (int)w[6], false, false);
    auto s57 = __builtin_amdgcn_permlane32_swap((int)w[5], (int)w[7], false, false);

    PackU pa0, pa1;
    pa0.u = (uint4v){(unsigned)s02[0], (unsigned)s13[0], (unsigned)s02[1], (unsigned)s13[1]};
    pa1.u = (uint4v){(unsigned)s46[0], (unsigned)s57[0], (unsigned)s46[1], (unsigned)s57[1]};

    acc0 = __builtin_amdgcn_mfma_f32_32x32x16_bf16(pa0.h, vf00, acc0, 0, 0, 0);
    acc1 = __builtin_amdgcn_mfma_f32_32x32x16_bf16(pa0.h, vf01, acc1, 0, 0, 0);
    acc0 = __builtin_amdgcn_mfma_f32_32x32x16_bf16(pa1.h, vf10, acc0, 0, 0, 0);
    acc1 = __builtin_amdgcn_mfma_f32_32x32x16_bf16(pa1.h, vf11, acc1, 0, 0, 0);
  }

  float lsum = (ls[0] + ls[1]) + (ls[2] + ls[3]);
  // within-wave: partner half-wave holds the other 16 keys of every tile
  lsum += __shfl_xor(lsum, 32);

  // merge the two key-halves (plain sums -> addition suffices)
  float* mb = LB + (size_t)qrow*64*33 + (size_t)lane*33;
  if (khalf) {
    #pragma unroll
    for (int r = 0; r < 16; ++r) { mb[r] = acc0[r]; mb[16+r] = acc1[r]; }
    mb[32] = lsum;
  }
  __syncthreads();
  if (!khalf) {
    #pragma unroll
    for (int r = 0; r < 16; ++r) { acc0[r] += mb[r]; acc1[r] += mb[16+r]; }
    lsum += mb[32];
  }
  __syncthreads();
  if (khalf) return;

  float sc = edge_w(wi, ph) * edge_w(wj, lo) / lsum;   // lane's query = lo
  int qh = h0 + ph;
  float* ob = outacc + (size_t)b*Cn*HWn + (size_t)qh*Wn + w0;
  float* T = LB + (size_t)qrow*1056;   // [32][33] per qrow wave

  // acc layout: D[query=(r&3)+8*(r>>2)+4*hi][ch=lo]; transpose so atomics
  // are coalesced along w (query) with ch strided.
  #pragma unroll
  for (int r = 0; r < 16; ++r) T[((r&3) + 8*(r>>2) + 4*hi)*33 + lo] = acc0[r];
  #pragma unroll
  for (int rr = 0; rr < 16; ++rr)
    atomicAdd(ob + (size_t)(2*rr + hi)*HWn + lo, T[lo*33 + 2*rr + hi] * sc);
  #pragma unroll
  for (int r = 0; r < 16; ++r) T[((r&3) + 8*(r>>2) + 4*hi)*33 + lo] = acc1[r];
  #pragma unroll
  for (int rr = 0; rr < 16; ++rr)
    atomicAdd(ob + (size_t)(32 + 2*rr + hi)*HWn + lo, T[lo*33 + 2*rr + hi] * sc);
}

// ---------------- final blend: out = x + gamma * acc/(cnt+1e-8) ----------------
__global__ __launch_bounds__(256) void final_kernel(
    const float* __restrict__ x, const float* __restrict__ gamma,
    float* __restrict__ out)
{
  int idx4 = blockIdx.x * 256 + threadIdx.x;
  int w4    = idx4 % (Wn/4);
  int rowid = idx4 / (Wn/4);
  int h = rowid % Hn;
  float g = gamma[0];
  float rs = covsum(h);
  int w0 = w4*4;
  float c0 = rs * covsum(w0+0) + 1e-8f;
  float c1 = rs * covsum(w0+1) + 1e-8f;
  float c2 = rs * covsum(w0+2) + 1e-8f;
  float c3 = rs * covsum(w0+3) + 1e-8f;
  float4 xv = ((const float4*)x)[idx4];
  float4 av = ((float4*)out)[idx4];
  float4 r;
  r.x = xv.x + g * av.x / c0;
  r.y = xv.y + g * av.y / c1;
  r.z = xv.z + g * av.z / c2;
  r.w = xv.w + g * av.w / c3;
  ((float4*)out)[idx4] = r;
}

extern "C" void kernel_launch(void* const* d_in, const int* in_sizes, int n_in,
                              void* d_out, int out_size, void* d_ws, size_t ws_size,
                              hipStream_t stream) {
  const float* x     = (const float*)d_in[0];
  const float* Wq    = (const float*)d_in[1];
  const float* bq    = (const float*)d_in[2];
  const float* Wk    = (const float*)d_in[3];
  const float* bk    = (const float*)d_in[4];
  const float* Wv    = (const float*)d_in[5];
  const float* bv    = (const float*)d_in[6];
  const float* gamma = (const float*)d_in[7];
  float* out = (float*)d_out;

  __bf16* qb  = (__bf16*)d_ws;                       // B*H*W*8
  __bf16* kb  = qb + (size_t)Bn*HWn*8;               // B*H*W*8
  __bf16* vb2 = kb + (size_t)Bn*HWn*8;               // B*C*H*W (w8-tiled)

  hipMemsetAsync(d_out, 0, (size_t)out_size * sizeof(float), stream);
  qkv_kernel<<<(Bn*HWn/256)*3, 256, 0, stream>>>(x, Wq, bq, Wk, bk, Wv, bv, qb, kb, vb2);
  attn_kernel<<<Bn*NHn*NWn*8, 512, 0, stream>>>(qb, kb, vb2, out);
  final_kernel<<<(Bn*Cn*HWn/4)/256, 256, 0, stream>>>(x, gamma, out);
}

// Round 7
// 106.574 us; speedup vs baseline: 8.7439x; 1.1772x over previous
//
#include <hip/hip_runtime.h>

#define Bn 2
#define Cn 64
#define Hn 224
#define Wn 224
#define HWn (Hn*Wn)
#define WSn 32
#define OVn 8
#define STRIDEn 24
#define NHn 9
#define NWn 9
#define NWT 28                 // W/8 tiles per row
#define VROW (NWT*Cn*8)        // 14336 elements per (b,h) row in vb2
#define QSCALE (1.44269504088896f/32.0f)

typedef __bf16 bf16x8 __attribute__((ext_vector_type(8)));
typedef __bf16 bf16x4 __attribute__((ext_vector_type(4)));
typedef float f32x16 __attribute__((ext_vector_type(16)));
typedef unsigned int uint4v __attribute__((ext_vector_type(4)));

union PackU { uint4v u; bf16x8 h; };
union BfPair { __bf16 h[2]; unsigned u; };

__device__ __forceinline__ float fast_exp2(float x) {
#if __has_builtin(__builtin_amdgcn_exp2f)
  return __builtin_amdgcn_exp2f(x);
#else
  return exp2f(x);
#endif
}

// fade weight factor for window index i, in-window position p
__device__ __forceinline__ float edge_w(int i, int p) {
  float w = 1.0f;
  if (i > 0 && p < OVn)            w *= (float)p * (1.0f/7.0f);
  if (i < NHn-1 && p >= WSn-OVn)   w *= (float)(WSn-1-p) * (1.0f/7.0f);
  return w;
}

// separable coverage sum
__device__ __forceinline__ float covsum(int h) {
  int ihi = h / STRIDEn; if (ihi > NHn-1) ihi = NHn-1;
  float s = edge_w(ihi, h - STRIDEn*ihi);
  int ilo = ihi - 1;
  if (ilo >= 0) {
    int p = h - STRIDEn*ilo;
    if (p < WSn) s += edge_w(ilo, p);
  }
  return s;
}

// ---------------- QKV projection: fp32 in, bf16 out ----------------
// 3-role split for wave parallelism (1568 -> 4704 waves):
//   role 0: q8 + k8;  role 1: v[0:32);  role 2: v[32:64).
// qb: [pix][8] bf16 PRE-SCALED by log2e/32.  kb: [pix][8] bf16.
// vb2: [b][h][w/8][c][w%8] bf16 (w8-tiled, coalesced PV fragment loads).
__global__ __launch_bounds__(256) void qkv_kernel(
    const float* __restrict__ x,
    const float* __restrict__ Wq, const float* __restrict__ bq,
    const float* __restrict__ Wk, const float* __restrict__ bk,
    const float* __restrict__ Wv, const float* __restrict__ bv,
    __bf16* __restrict__ qb, __bf16* __restrict__ kb, __bf16* __restrict__ vb2)
{
  __shared__ float sW[32*64];
  __shared__ float sb2[32];
  int bid = blockIdx.x;
  int pb = bid / 3, role = bid - pb*3;
  int tid = threadIdx.x;

  if (role == 0) {
    for (int i = tid; i < 8*64; i += 256) { sW[i] = Wq[i]; sW[512 + i] = Wk[i]; }
    if (tid < 8) { sb2[tid] = bq[tid]; sb2[8 + tid] = bk[tid]; }
  } else {
    const float* Wsrc = Wv + (size_t)(role-1)*32*64;
    for (int i = tid; i < 32*64; i += 256) sW[i] = Wsrc[i];
    if (tid < 32) sb2[tid] = bv[(role-1)*32 + tid];
  }
  __syncthreads();

  int pix = pb*256 + tid;                // B*H*W = 100352 = 392*256
  int b  = pix / HWn;
  int hw = pix - b * HWn;
  const float* xp = x + (size_t)b * Cn * HWn + hw;
  float xr[64];
  #pragma unroll
  for (int c = 0; c < 64; ++c) xr[c] = xp[(size_t)c * HWn];

  if (role == 0) {
    float q8[8], k8[8];
    #pragma unroll
    for (int o = 0; o < 8; ++o) {
      const float4* wrq = (const float4*)(sW + o*64);
      const float4* wrk = (const float4*)(sW + 512 + o*64);
      float sq = sb2[o], sk = sb2[8+o];
      #pragma unroll
      for (int c4 = 0; c4 < 16; ++c4) {
        float4 wq4 = wrq[c4]; float4 wk4 = wrk[c4];
        sq = fmaf(wq4.x, xr[4*c4+0], sq); sq = fmaf(wq4.y, xr[4*c4+1], sq);
        sq = fmaf(wq4.z, xr[4*c4+2], sq); sq = fmaf(wq4.w, xr[4*c4+3], sq);
        sk = fmaf(wk4.x, xr[4*c4+0], sk); sk = fmaf(wk4.y, xr[4*c4+1], sk);
        sk = fmaf(wk4.z, xr[4*c4+2], sk); sk = fmaf(wk4.w, xr[4*c4+3], sk);
      }
      q8[o] = sq; k8[o] = sk;
    }
    PackU qo, ko;
    #pragma unroll
    for (int o = 0; o < 8; ++o) {
      qo.h[o] = (__bf16)(q8[o] * QSCALE);
      ko.h[o] = (__bf16)k8[o];
    }
    *(uint4v*)(qb + (size_t)pix*8) = qo.u;
    *(uint4v*)(kb + (size_t)pix*8) = ko.u;
  } else {
    int h = hw / Wn, w = hw - h*Wn;
    __bf16* vo = vb2 + (((size_t)(b*Hn + h)*NWT + (w >> 3))*Cn + (size_t)(role-1)*32)*8 + (w & 7);
    for (int og = 0; og < 8; ++og) {
      #pragma unroll
      for (int t = 0; t < 4; ++t) {
        int o = og*4 + t;
        const float4* wr = (const float4*)(sW + o*64);
        float s = sb2[o];
        #pragma unroll
        for (int c4 = 0; c4 < 16; ++c4) {
          float4 w4 = wr[c4];
          s = fmaf(w4.x, xr[4*c4+0], s); s = fmaf(w4.y, xr[4*c4+1], s);
          s = fmaf(w4.z, xr[4*c4+2], s); s = fmaf(w4.w, xr[4*c4+3], s);
        }
        vo[(size_t)o * 8] = (__bf16)s;
      }
    }
  }
}

// ---------------- MFMA flash attention ----------------
// Block = 512 threads = 8 waves = one window x 4 query-rows x 2 key-halves.
// Grid = 162 windows * 8 row-groups = 1296 blocks.
// NO atomics: per-window outputs (wgt/lsum pre-applied) stored bf16 to ob2.
// launch_bounds min-waves MUST stay <=4: (512,8) caps VGPR at 64 -> acc spills
// to scratch -> 2.8 GB HBM traffic, 8x regression (measured round 4).
__global__ __launch_bounds__(512, 4) void attn_kernel(
    const __bf16* __restrict__ qb, const __bf16* __restrict__ kb,
    const __bf16* __restrict__ vb2, __bf16* __restrict__ ob2)
{
  // LDS: exchange slots 2*4*64*17 floats (34 KB), then reused as 8 transpose
  // tiles of [32][33] floats (33.8 KB). Max 8704 floats = 34816 B.
  __shared__ float LB[8704];

  // XCD swizzle: 1296 = 8*162; consecutive bidm (same window) on same XCD.
  int bid = blockIdx.x;
  int bidm = (bid & 7) * 162 + (bid >> 3);
  int win = bidm >> 3;            // 0..161
  int rg  = bidm & 7;             // row-group 0..7
  int b  = win / (NHn*NWn);
  int ij = win - b*(NHn*NWn);
  int wi = ij / NWn;
  int wj = ij - wi*NWn;

  int tid  = threadIdx.x;
  int widx = tid >> 6;            // wave 0..7
  int lane = tid & 63;
  int qrow = widx >> 1;           // 0..3
  int khalf = widx & 1;           // 0..1 (key rows 0..15 / 16..31)
  int ph = rg*4 + qrow;
  int lo = lane & 31, hi = lane >> 5;
  int h0 = wi*STRIDEn, w0 = wj*STRIDEn;

  // Q fragment (B operand): lane holds Q[query=lo][ch=8*hi+j]; hi lanes zeroed (ch 8..15 pad)
  bf16x8 qf = *(const bf16x8*)(qb + ((size_t)(b*Hn + h0 + ph)*Wn + w0 + lo) * 8);
  if (hi) qf = (bf16x8){};

  // K rows for this key-half; hi lanes duplicate (annihilated by qf==0 rows)
  const __bf16* kbase = kb + ((size_t)(b*Hn + h0 + khalf*16)*Wn + w0 + lo) * 8;
  // V in w8-tiled layout; vbase points at (ch=lo, wtile=w0/8 + hi)
  const __bf16* vbase = vb2 + ((((size_t)(b*Hn + h0 + khalf*16))*NWT + (w0>>3))*Cn + lo)*8
                        + (size_t)hi*512;

  f32x16 acc0 = {}, acc1 = {};
  float ls[4] = {0.f, 0.f, 0.f, 0.f};   // 4-way partial sums: break the serial add chain

  #pragma unroll 2
  for (int kt = 0; kt < 16; ++kt) {
    bf16x8 kf = *(const bf16x8*)(kbase + (size_t)kt*Wn*8);

    const __bf16* vk = vbase + (size_t)kt*VROW;
    bf16x8 vf00 = *(const bf16x8*)(vk);           // keys 8*hi+j,    ch lo
    bf16x8 vf01 = *(const bf16x8*)(vk + 256);     // keys 8*hi+j,    ch lo+32
    bf16x8 vf10 = *(const bf16x8*)(vk + 1024);    // keys 16+8*hi+j, ch lo
    bf16x8 vf11 = *(const bf16x8*)(vk + 1280);    // keys 16+8*hi+j, ch lo+32

    // S[key][query]: key=(r&3)+8*(r>>2)+4*hi, query=lo. Scores in log2 domain.
    f32x16 s = __builtin_amdgcn_mfma_f32_32x32x16_bf16(kf, qf, (f32x16){}, 0, 0, 0);

    unsigned w[8];
    #pragma unroll
    for (int d = 0; d < 8; ++d) {
      float a  = fast_exp2(s[2*d]);
      float b2 = fast_exp2(s[2*d+1]);
      ls[d & 3] += a + b2;
      BfPair pr; pr.h[0] = (__bf16)a; pr.h[1] = (__bf16)b2;
      w[d] = pr.u;
    }
    // permlane32_swap: one op yields BOTH PV-fragment words.
    auto s02 = __builtin_amdgcn_permlane32_swap((int)w[0], (int)w[2], false, false);
    auto s13 = __builtin_amdgcn_permlane32_swap((int)w[1], (int)w[3], false, false);
    auto s46 = __builtin_amdgcn_permlane32_swap((int)w[4], (int)w[6], false, false);
    auto s57 = __builtin_amdgcn_permlane32_swap((int)w[5], (int)w[7], false, false);

    PackU pa0, pa1;
    pa0.u = (uint4v){(unsigned)s02[0], (unsigned)s13[0], (unsigned)s02[1], (unsigned)s13[1]};
    pa1.u = (uint4v){(unsigned)s46[0], (unsigned)s57[0], (unsigned)s46[1], (unsigned)s57[1]};

    acc0 = __builtin_amdgcn_mfma_f32_32x32x16_bf16(pa0.h, vf00, acc0, 0, 0, 0);
    acc1 = __builtin_amdgcn_mfma_f32_32x32x16_bf16(pa0.h, vf01, acc1, 0, 0, 0);
    acc0 = __builtin_amdgcn_mfma_f32_32x32x16_bf16(pa1.h, vf10, acc0, 0, 0, 0);
    acc1 = __builtin_amdgcn_mfma_f32_32x32x16_bf16(pa1.h, vf11, acc1, 0, 0, 0);
  }

  float lsum = (ls[0] + ls[1]) + (ls[2] + ls[3]);
  // within-wave: partner half-wave holds the other 16 keys of every row
  lsum += __shfl_xor(lsum, 32);

  // symmetric key-half merge: khalf0 finishes ch 0..31 (acc0), khalf1 ch 32..63 (acc1).
  float* exA = LB        + ((size_t)qrow*64 + lane)*17;   // khalf0 deposits acc1+lsum
  float* exB = LB + 4352 + ((size_t)qrow*64 + lane)*17;   // khalf1 deposits acc0+lsum
  if (khalf) {
    #pragma unroll
    for (int r = 0; r < 16; ++r) exB[r] = acc0[r];
    exB[16] = lsum;
  } else {
    #pragma unroll
    for (int r = 0; r < 16; ++r) exA[r] = acc1[r];
    exA[16] = lsum;
  }
  __syncthreads();
  f32x16 am;
  if (khalf) {
    #pragma unroll
    for (int r = 0; r < 16; ++r) am[r] = acc1[r] + exA[r];
    lsum += exA[16];
  } else {
    #pragma unroll
    for (int r = 0; r < 16; ++r) am[r] = acc0[r] + exB[r];
    lsum += exB[16];
  }
  __syncthreads();   // exchange slots free; reuse LDS as transpose tiles

  float sc = edge_w(wi, ph) * edge_w(wj, lo) / lsum;   // lane's query col = lo
  float* T = LB + (size_t)widx*1056;                   // per-wave [32][33]

  // am layout: D[querycol=(r&3)+8*(r>>2)+4*hi][ch(lane-half dependent)]; transpose
  // so stores run along querycol (contiguous p in ob2).
  #pragma unroll
  for (int r = 0; r < 16; ++r) T[((r&3) + 8*(r>>2) + 4*hi)*33 + lo] = am[r];

  // ob2 layout: [win(162)][c(64)][p(1024)], p = ph*32 + querycol
  __bf16* ob = ob2 + ((size_t)(b*81 + wi*9 + wj)*64 + khalf*32)*1024 + ph*32;
  #pragma unroll
  for (int rr = 0; rr < 16; ++rr) {
    float val = T[lo*33 + 2*rr + hi] * sc;
    ob[(size_t)(2*rr + hi)*1024 + lo] = (__bf16)val;
  }
}

// ---------------- final blend: gather <=4 window contributions ----------------
// out = x + gamma * (sum of stored wgt*ow/lsum) / (cnt + 1e-8), cnt separable.
// Window-coverage boundaries (24*j and 24*j+32) are multiples of 4, so an
// aligned w4-group has a constant covering-window set -> bf16x4 loads.
__global__ __launch_bounds__(256) void final_kernel(
    const float* __restrict__ x, const float* __restrict__ gamma,
    const __bf16* __restrict__ ob2, float* __restrict__ out)
{
  int idx4 = blockIdx.x * 256 + threadIdx.x;   // < B*C*H*W/4
  int w4    = idx4 % (Wn/4);
  int rowid = idx4 / (Wn/4);
  int h  = rowid % Hn;
  int cb = rowid / Hn;          // b*64 + c
  int c  = cb & 63;
  int b  = cb >> 6;
  int w0 = w4*4;

  int ihi = h  / STRIDEn; if (ihi > NHn-1) ihi = NHn-1;
  int jhi = w0 / STRIDEn; if (jhi > NWn-1) jhi = NWn-1;

  float s0 = 0.f, s1 = 0.f, s2 = 0.f, s3 = 0.f;
  #pragma unroll
  for (int dy = 0; dy < 2; ++dy) {
    int wi = ihi - dy;
    if (wi < 0) continue;
    int ph = h - STRIDEn*wi;
    if (ph >= WSn) continue;
    #pragma unroll
    for (int dx = 0; dx < 2; ++dx) {
      int wj = jhi - dx;
      if (wj < 0) continue;
      int pw = w0 - STRIDEn*wj;
      if (pw >= WSn) continue;
      const __bf16* src = ob2 + (((size_t)(b*81 + wi*9 + wj)*64 + c) << 10) + ph*WSn + pw;
      bf16x4 v = *(const bf16x4*)src;
      s0 += (float)v[0]; s1 += (float)v[1]; s2 += (float)v[2]; s3 += (float)v[3];
    }
  }

  float g = gamma[0];
  float rs = covsum(h);
  float i0 = 1.0f / (rs * covsum(w0+0) + 1e-8f);
  float i1 = 1.0f / (rs * covsum(w0+1) + 1e-8f);
  float i2 = 1.0f / (rs * covsum(w0+2) + 1e-8f);
  float i3 = 1.0f / (rs * covsum(w0+3) + 1e-8f);
  float4 xv = ((const float4*)x)[idx4];
  float4 r;
  r.x = xv.x + g * s0 * i0;
  r.y = xv.y + g * s1 * i1;
  r.z = xv.z + g * s2 * i2;
  r.w = xv.w + g * s3 * i3;
  ((float4*)out)[idx4] = r;
}

extern "C" void kernel_launch(void* const* d_in, const int* in_sizes, int n_in,
                              void* d_out, int out_size, void* d_ws, size_t ws_size,
                              hipStream_t stream) {
  const float* x     = (const float*)d_in[0];
  const float* Wq    = (const float*)d_in[1];
  const float* bq    = (const float*)d_in[2];
  const float* Wk    = (const float*)d_in[3];
  const float* bk    = (const float*)d_in[4];
  const float* Wv    = (const float*)d_in[5];
  const float* bv    = (const float*)d_in[6];
  const float* gamma = (const float*)d_in[7];
  float* out = (float*)d_out;

  __bf16* qb  = (__bf16*)d_ws;                       // B*H*W*8          (1.6 MB)
  __bf16* kb  = qb  + (size_t)Bn*HWn*8;              // B*H*W*8          (1.6 MB)
  __bf16* vb2 = kb  + (size_t)Bn*HWn*8;              // B*C*H*W w8-tiled (12.8 MB)
  __bf16* ob2 = vb2 + (size_t)Bn*Cn*HWn;             // 162*64*1024      (21.2 MB)

  qkv_kernel<<<(Bn*HWn/256)*3, 256, 0, stream>>>(x, Wq, bq, Wk, bk, Wv, bv, qb, kb, vb2);
  attn_kernel<<<Bn*NHn*NWn*8, 512, 0, stream>>>(qb, kb, vb2, ob2);
  final_kernel<<<(Bn*Cn*HWn/4)/256, 256, 0, stream>>>(x, gamma, ob2, out);
}